// Round 1
// baseline (1166.976 us; speedup 1.0000x reference)
//
#include <hip/hip_runtime.h>
#include <math.h>

#define Hn 50
#define Dn 8
#define Tn 512
#define BB 4              // batch rows per block (hi rows 0..3, lo rows 4..7, 8..15 pad)
#define NBLK 512          // 2048 / BB  -> 2 blocks per CU
#define GP 260            // gate-buffer row pad (floats)

typedef __attribute__((ext_vector_type(8))) short short8;   // 8 bf16 (4 VGPRs)
typedef __attribute__((ext_vector_type(4))) float f32x4;

__device__ __forceinline__ float fexp2_(float x) {
#if __has_builtin(__builtin_amdgcn_exp2f)
    return __builtin_amdgcn_exp2f(x);
#else
    return exp2f(x);
#endif
}
__device__ __forceinline__ float frcp_(float x) {
#if __has_builtin(__builtin_amdgcn_rcpf)
    return __builtin_amdgcn_rcpf(x);
#else
    return 1.0f / x;
#endif
}
__device__ __forceinline__ float sigmoidf_(float x) {
    return frcp_(1.0f + fexp2_(-1.44269504f * x));
}
__device__ __forceinline__ float tanhf_(float x) {
    return 2.0f * sigmoidf_(2.0f * x) - 1.0f;
}
__device__ __forceinline__ float bf2f(short s) {
    return __uint_as_float(((unsigned)(unsigned short)s) << 16);
}
// truncation split: v = hi + lo + O(2^-17 v)
__device__ __forceinline__ void split_bf(float v, short& hi, short& lo) {
    hi = (short)(__float_as_uint(v) >> 16);
    const float r = v - bf2f(hi);
    lo = (short)(__float_as_uint(r) >> 16);
}
// one LSTM cell update: gm + glo are the two gate partial rows (main / lo)
__device__ __forceinline__ float lstm_cell(const f32x4 gm, const f32x4 glo, float& c) {
    const float gi = gm.x + glo.x;
    const float gf = gm.y + glo.y;
    const float gg = gm.z + glo.z;
    const float go = gm.w + glo.w;
    c = sigmoidf_(gf) * c + sigmoidf_(gi) * tanhf_(gg);
    return sigmoidf_(go) * tanhf_(c);
}

// Persistent 2-layer LSTM, 2 blocks/CU for phase overlap (r13).
// hi/lo batch-row packing: A-pack rows 0..3 = bf16-hi of batches 0..3,
// rows 4..7 = bf16-lo, rows 8..15 = 0. One accumulator per tile gets
//   rows 0..3 : a_hi * (B_hi + B_lo)      (2 MFMAs per kstep: x B_hi, x B_lo)
//   rows 4..7 : a_lo * (B_hi + B_lo)      (a_lo*B_lo term ~2^-18, negligible)
// and the activation thread sums row b + row 4+b in fp32.
// A-pack aPS[s=0..3][m=16][k32=40]:
//   s0: h0 cells 0..31 | s1: h0 cells 32..49, x d0..7 at k32 18..25
//   s2: h1 cells 0..31 | s3: h1 cells 32..49
// Layouts (m89/m120-verified): C/D n=lane&15, m=(lane>>4)*4+reg;
// A[m=lane&15][k=(lane>>4)*8+j]; B[k=(lane>>4)*8+j][n=lane&15].
__global__ __launch_bounds__(512, 4) void lstm2_kernel(
    const float* __restrict__ x,
    const float* __restrict__ Wih0, const float* __restrict__ Whh0,
    const float* __restrict__ bih0, const float* __restrict__ bhh0,
    const float* __restrict__ Wih1, const float* __restrict__ Whh1,
    const float* __restrict__ bih1, const float* __restrict__ bhh1,
    const float* __restrict__ Wlin, const float* __restrict__ blin,
    float* __restrict__ out)
{
    const int tid  = threadIdx.x;     // 0..511
    const int b0   = blockIdx.x * BB;
    const int w    = tid >> 6;        // wave 0..7
    const int lane = tid & 63;
    const int quad = lane >> 4;
    const int col  = lane & 15;
    const int ntw  = (w < 6) ? 2 : ((w == 6) ? 1 : 0);  // N-tiles this wave
    const int tb   = 2 * w;

    __shared__ __align__(16) short aPS[4 * 16 * 40];     // unified hi/lo A-pack
    __shared__ __align__(16) float gL[2][8][GP];         // [layer][row: 0-3 main, 4-7 lo][n]
    __shared__ float h1f[Hn * BB];                       // fp32 h1 at t=Tn-1

    // ---- B-fragments + bias in registers (cell-major columns) ----
    short8 B0[2][2][2];   // [tile][kstep][hi/lo]
    short8 B1[2][4][2];   // [tile][kstep][hi/lo]  (s0,1 = Wih1; s2,3 = Whh1)
    float  bw0[2], bw1[2];
    #pragma unroll
    for (int tt = 0; tt < 2; ++tt) {
        const int ng = (tb + tt) * 16 + col;       // cell-major gate column
        const int cl = ng >> 2, g = ng & 3;
        const bool on = (tt < ntw) && (cl < Hn);
        const int grow = g * Hn + cl;
        bw0[tt] = on ? (bih0[grow] + bhh0[grow]) : 0.f;
        bw1[tt] = on ? (bih1[grow] + bhh1[grow]) : 0.f;
        #pragma unroll
        for (int s = 0; s < 2; ++s)
            #pragma unroll
            for (int j = 0; j < 8; ++j) {
                const int k = 32 * s + quad * 8 + j;
                float v = 0.f;
                if (on) {
                    if (k < Hn)           v = Whh0[grow * Hn + k];
                    else if (k < Hn + Dn) v = Wih0[grow * Dn + (k - Hn)];
                }
                short hi, lo; split_bf(v, hi, lo);
                B0[tt][s][0][j] = hi; B0[tt][s][1][j] = lo;
            }
        #pragma unroll
        for (int s = 0; s < 4; ++s)
            #pragma unroll
            for (int j = 0; j < 8; ++j) {
                const int k = 32 * s + quad * 8 + j;
                float v = 0.f;
                if (on) {
                    if (k < Hn)                      v = Wih1[grow * Hn + k];
                    else if (k >= 64 && k < 64 + Hn) v = Whh1[grow * Hn + (k - 64)];
                    // k 50..63: zero -> shared-pack x columns contribute 0
                }
                short hi, lo; split_bf(v, hi, lo);
                B1[tt][s][0][j] = hi; B1[tt][s][1][j] = lo;
            }
    }

    // ---- init: zero A-pack (rows 8..15 must stay 0); stage x(0) ----
    for (int i = tid; i < 4 * 16 * 40; i += 512) aPS[i] = 0;
    __syncthreads();
    if (tid < 32) {
        const int xb = tid >> 3, xd = tid & 7;
        const float f = x[((size_t)(b0 + xb) * Tn + 0) * Dn + xd];
        short hi, lo; split_bf(f, hi, lo);
        aPS[(1 * 16 + xb) * 40 + 18 + xd]     = hi;
        aPS[(1 * 16 + 4 + xb) * 40 + 18 + xd] = lo;
    }
    __syncthreads();

    // ---- activation-thread constants: one (layer, cell, batch) each ----
    const bool actT = (tid < 400);            // 2 layers * 50 cells * 4 batches
    const int  al   = (tid >= 200) ? 1 : 0;
    const int  ar   = tid - 200 * al;
    const int  acell = ar >> 2;               // 0..49
    const int  ab    = ar & 3;                // 0..3
    const int  asb   = al ? 2 : 0;            // aPS s-base for this layer
    float cc = 0.f;                           // c-state (layer al, cell acell, batch ab)
    float xreg = 0.f;                         // wave-7 x staging register

    // ============ prologue: gates0(0) ; act0(0) ============
    if (ntw > 0) {
        f32x4 D0[2];
        #pragma unroll
        for (int tt = 0; tt < 2; ++tt) {
            const float z = (quad == 0) ? bw0[tt] : 0.f;
            f32x4 zi = {z, z, z, z}; D0[tt] = zi;
        }
        #pragma unroll
        for (int s = 0; s < 2; ++s) {
            const short8 a = *(const short8*)&aPS[(s * 16 + col) * 40 + quad * 8];
            #pragma unroll
            for (int tt = 0; tt < 2; ++tt)
                if (tt < ntw) {
                    D0[tt] = __builtin_amdgcn_mfma_f32_16x16x32_bf16(a, B0[tt][0 + s][0], D0[tt], 0,0,0);
                    D0[tt] = __builtin_amdgcn_mfma_f32_16x16x32_bf16(a, B0[tt][0 + s][1], D0[tt], 0,0,0);
                }
        }
        if (quad < 2) {
            #pragma unroll
            for (int tt = 0; tt < 2; ++tt)
                if (tt < ntw) {
                    const int n = (tb + tt) * 16 + col;
                    #pragma unroll
                    for (int r = 0; r < 4; ++r) gL[0][quad * 4 + r][n] = D0[tt][r];
                }
        }
    } else if (lane < 32) {
        xreg = x[((size_t)(b0 + (lane >> 3)) * Tn + 1) * Dn + (lane & 7)];
    }
    __syncthreads();
    if (actT && al == 0) {
        const f32x4 gm  = *(const f32x4*)&gL[0][ab][4 * acell];
        const f32x4 glo = *(const f32x4*)&gL[0][4 + ab][4 * acell];
        const float h = lstm_cell(gm, glo, cc);
        short hi, lo; split_bf(h, hi, lo);
        const int si = (acell >> 5), k32 = acell & 31;
        aPS[(si * 16 + ab) * 40 + k32]     = hi;
        aPS[(si * 16 + 4 + ab) * 40 + k32] = lo;
    } else if (w == 7 && lane < 32) {
        short hi, lo; split_bf(xreg, hi, lo);
        aPS[(1 * 16 + (lane >> 3)) * 40 + 18 + (lane & 7)]     = hi;
        aPS[(1 * 16 + 4 + (lane >> 3)) * 40 + 18 + (lane & 7)] = lo;
    }
    __syncthreads();

    // ============ main loop: t = 1 .. Tn-1 ============
    for (int t = 1; t < Tn; ++t) {
        // ---- phase M: gates0(t) + gates1(t-1), shared A-frags ----
        if (ntw > 0) {
            f32x4 D0[2], D1[2];
            #pragma unroll
            for (int tt = 0; tt < 2; ++tt) {
                const float z0 = (quad == 0) ? bw0[tt] : 0.f;
                const float z1 = (quad == 0) ? bw1[tt] : 0.f;
                f32x4 a0 = {z0, z0, z0, z0}; D0[tt] = a0;
                f32x4 a1 = {z1, z1, z1, z1}; D1[tt] = a1;
            }
            #pragma unroll
            for (int s = 0; s < 2; ++s) {       // shared [h0|x] ksteps
                const short8 a = *(const short8*)&aPS[(s * 16 + col) * 40 + quad * 8];
                #pragma unroll
                for (int tt = 0; tt < 2; ++tt)
                    if (tt < ntw) {
                        D0[tt] = __builtin_amdgcn_mfma_f32_16x16x32_bf16(a, B0[tt][s][0], D0[tt], 0,0,0);
                        D0[tt] = __builtin_amdgcn_mfma_f32_16x16x32_bf16(a, B0[tt][s][1], D0[tt], 0,0,0);
                        D1[tt] = __builtin_amdgcn_mfma_f32_16x16x32_bf16(a, B1[tt][s][0], D1[tt], 0,0,0);
                        D1[tt] = __builtin_amdgcn_mfma_f32_16x16x32_bf16(a, B1[tt][s][1], D1[tt], 0,0,0);
                    }
            }
            #pragma unroll
            for (int s = 2; s < 4; ++s) {       // h1 ksteps
                const short8 a = *(const short8*)&aPS[(s * 16 + col) * 40 + quad * 8];
                #pragma unroll
                for (int tt = 0; tt < 2; ++tt)
                    if (tt < ntw) {
                        D1[tt] = __builtin_amdgcn_mfma_f32_16x16x32_bf16(a, B1[tt][s][0], D1[tt], 0,0,0);
                        D1[tt] = __builtin_amdgcn_mfma_f32_16x16x32_bf16(a, B1[tt][s][1], D1[tt], 0,0,0);
                    }
            }
            if (quad < 2) {
                #pragma unroll
                for (int tt = 0; tt < 2; ++tt)
                    if (tt < ntw) {
                        const int n = (tb + tt) * 16 + col;
                        #pragma unroll
                        for (int r = 0; r < 4; ++r) {
                            gL[0][quad * 4 + r][n] = D0[tt][r];
                            gL[1][quad * 4 + r][n] = D1[tt][r];
                        }
                    }
            }
        } else if (lane < 32) {
            const int tn = (t + 1 < Tn) ? (t + 1) : (Tn - 1);
            xreg = x[((size_t)(b0 + (lane >> 3)) * Tn + tn) * Dn + (lane & 7)];
        }
        __syncthreads();

        // ---- phase A: act1(t-1) and act0(t) on disjoint threads ----
        if (actT) {
            const f32x4 gm  = *(const f32x4*)&gL[al][ab][4 * acell];
            const f32x4 glo = *(const f32x4*)&gL[al][4 + ab][4 * acell];
            const float h = lstm_cell(gm, glo, cc);
            short hi, lo; split_bf(h, hi, lo);
            const int si = asb + (acell >> 5), k32 = acell & 31;
            aPS[(si * 16 + ab) * 40 + k32]     = hi;
            aPS[(si * 16 + 4 + ab) * 40 + k32] = lo;
        } else if (w == 7 && lane < 32) {
            short hi, lo; split_bf(xreg, hi, lo);
            aPS[(1 * 16 + (lane >> 3)) * 40 + 18 + (lane & 7)]     = hi;
            aPS[(1 * 16 + 4 + (lane >> 3)) * 40 + 18 + (lane & 7)] = lo;
        }
        __syncthreads();
    }

    // ============ epilogue: gates1(Tn-1) ; act1(Tn-1) ============
    if (ntw > 0) {
        f32x4 D1[2];
        #pragma unroll
        for (int tt = 0; tt < 2; ++tt) {
            const float z = (quad == 0) ? bw1[tt] : 0.f;
            f32x4 zi = {z, z, z, z}; D1[tt] = zi;
        }
        #pragma unroll
        for (int s = 0; s < 4; ++s) {
            const short8 a = *(const short8*)&aPS[(s * 16 + col) * 40 + quad * 8];
            #pragma unroll
            for (int tt = 0; tt < 2; ++tt)
                if (tt < ntw) {
                    D1[tt] = __builtin_amdgcn_mfma_f32_16x16x32_bf16(a, B1[tt][s][0], D1[tt], 0,0,0);
                    D1[tt] = __builtin_amdgcn_mfma_f32_16x16x32_bf16(a, B1[tt][s][1], D1[tt], 0,0,0);
                }
        }
        if (quad < 2) {
            #pragma unroll
            for (int tt = 0; tt < 2; ++tt)
                if (tt < ntw) {
                    const int n = (tb + tt) * 16 + col;
                    #pragma unroll
                    for (int r = 0; r < 4; ++r) gL[1][quad * 4 + r][n] = D1[tt][r];
                }
        }
    }
    __syncthreads();
    if (actT && al == 1) {
        const f32x4 gm  = *(const f32x4*)&gL[1][ab][4 * acell];
        const f32x4 glo = *(const f32x4*)&gL[1][4 + ab][4 * acell];
        const float h = lstm_cell(gm, glo, cc);
        h1f[acell * BB + ab] = h;
    }
    __syncthreads();

    // ---- head: out[b] = h1_last . Wlin + blin (fp32 path) ----
    if (tid < BB) {
        float o = blin[0];
        #pragma unroll
        for (int k = 0; k < Hn; ++k) o += Wlin[k] * h1f[k * BB + tid];
        out[b0 + tid] = o;
    }
}

extern "C" void kernel_launch(void* const* d_in, const int* in_sizes, int n_in,
                              void* d_out, int out_size, void* d_ws, size_t ws_size,
                              hipStream_t stream) {
    const float* x    = (const float*)d_in[0];
    const float* Wih0 = (const float*)d_in[1];
    const float* Whh0 = (const float*)d_in[2];
    const float* bih0 = (const float*)d_in[3];
    const float* bhh0 = (const float*)d_in[4];
    const float* Wih1 = (const float*)d_in[5];
    const float* Whh1 = (const float*)d_in[6];
    const float* bih1 = (const float*)d_in[7];
    const float* bhh1 = (const float*)d_in[8];
    const float* Wlin = (const float*)d_in[9];
    const float* blin = (const float*)d_in[10];
    float* out = (float*)d_out;

    lstm2_kernel<<<NBLK, 512, 0, stream>>>(x, Wih0, Whh0, bih0, bhh0,
                                           Wih1, Whh1, bih1, bhh1,
                                           Wlin, blin, out);
}

// Round 2
// 632.079 us; speedup vs baseline: 1.8462x; 1.8462x over previous
//
#include <hip/hip_runtime.h>
#include <math.h>

#define Hn 50
#define Dn 8
#define Tn 512
#define BB 8              // batch rows per block: M-rows 0..7 = bf16-hi, 8..15 = bf16-lo
#define NBLK 256          // 2048 / BB -> 1 block/CU (register-bound, see r13 post-mortem)
#define GP 260            // gate-buffer row pad (floats)

typedef __attribute__((ext_vector_type(8))) short short8;   // 8 bf16 (4 VGPRs)
typedef __attribute__((ext_vector_type(4))) float f32x4;

__device__ __forceinline__ float fexp2_(float x) {
#if __has_builtin(__builtin_amdgcn_exp2f)
    return __builtin_amdgcn_exp2f(x);
#else
    return exp2f(x);
#endif
}
__device__ __forceinline__ float frcp_(float x) {
#if __has_builtin(__builtin_amdgcn_rcpf)
    return __builtin_amdgcn_rcpf(x);
#else
    return 1.0f / x;
#endif
}
__device__ __forceinline__ float sigmoidf_(float x) {
    return frcp_(1.0f + fexp2_(-1.44269504f * x));
}
__device__ __forceinline__ float tanhf_(float x) {
    return 2.0f * sigmoidf_(2.0f * x) - 1.0f;
}
__device__ __forceinline__ float bf2f(short s) {
    return __uint_as_float(((unsigned)(unsigned short)s) << 16);
}
// truncation split: v = hi + lo + O(2^-17 v)
__device__ __forceinline__ void split_bf(float v, short& hi, short& lo) {
    hi = (short)(__float_as_uint(v) >> 16);
    const float r = v - bf2f(hi);
    lo = (short)(__float_as_uint(r) >> 16);
}
// one LSTM cell update: gm + glo are the hi-row / lo-row gate partials
__device__ __forceinline__ float lstm_cell(const f32x4 gm, const f32x4 glo, float& c) {
    const float gi = gm.x + glo.x;
    const float gf = gm.y + glo.y;
    const float gg = gm.z + glo.z;
    const float go = gm.w + glo.w;
    c = sigmoidf_(gf) * c + sigmoidf_(gi) * tanhf_(gg);
    return sigmoidf_(go) * tanhf_(c);
}

// Persistent 2-layer LSTM (r14): hi/lo BATCH-ROW packing at BB=8.
// A-pack rows 0..7 = bf16-hi of batches 0..7, rows 8..15 = bf16-lo.
// Per (kstep, tile) only 2 MFMAs (x B_hi, x B_lo); one accumulator holds
//   rows 0..7 : a_hi * (B_hi + B_lo)
//   rows 8..15: a_lo * (B_hi + B_lo)
// and the activation thread sums row b + row 8+b in fp32 — this INCLUDES the
// a_lo*B_lo term r12/r13 dropped, so numerics are slightly better.
// vs r12: MFMAs/wave/step 36 -> 24, A-frag b128 reads 8 -> 4, all 4 quads
// active in the gate write (was quad<2). 1 block/CU (register-bound: B-frags
// are 96 regs; r13 proved forcing 2 blocks/CU spills to scratch, 40MB/step).
// A-pack aPS[s=0..3][m=16][k32=40]:
//   s0: h0 cells 0..31 | s1: h0 cells 32..49, x d0..7 at k32 18..25
//   s2: h1 cells 0..31 | s3: h1 cells 32..49
// Layouts (m89/m120-verified): C/D n=lane&15, m=(lane>>4)*4+reg;
// A[m=lane&15][k=(lane>>4)*8+j]; B[k=(lane>>4)*8+j][n=lane&15].
__global__ __launch_bounds__(512, 1) void lstm2_kernel(
    const float* __restrict__ x,
    const float* __restrict__ Wih0, const float* __restrict__ Whh0,
    const float* __restrict__ bih0, const float* __restrict__ bhh0,
    const float* __restrict__ Wih1, const float* __restrict__ Whh1,
    const float* __restrict__ bih1, const float* __restrict__ bhh1,
    const float* __restrict__ Wlin, const float* __restrict__ blin,
    float* __restrict__ out)
{
    const int tid  = threadIdx.x;     // 0..511
    const int b0   = blockIdx.x * BB;
    const int w    = tid >> 6;        // wave 0..7
    const int lane = tid & 63;
    const int quad = lane >> 4;
    const int col  = lane & 15;
    const int ntw  = (w < 6) ? 2 : ((w == 6) ? 1 : 0);  // N-tiles this wave
    const int tb   = 2 * w;

    __shared__ __align__(16) short aPS[4 * 16 * 40];     // hi/lo row-packed A
    __shared__ __align__(16) float gL[2][16][GP];        // [layer][m-row][n]
    __shared__ float h1f[Hn * BB];                       // fp32 h1 at t=Tn-1

    // ---- B-fragments + bias in registers (cell-major columns) ----
    short8 B0[2][2][2];   // [tile][kstep][hi/lo]
    short8 B1[2][4][2];   // [tile][kstep][hi/lo]  (s0,1 = Wih1; s2,3 = Whh1)
    float  bw0[2], bw1[2];
    #pragma unroll
    for (int tt = 0; tt < 2; ++tt) {
        const int ng = (tb + tt) * 16 + col;       // cell-major gate column
        const int cl = ng >> 2, g = ng & 3;
        const bool on = (tt < ntw) && (cl < Hn);
        const int grow = g * Hn + cl;
        bw0[tt] = on ? (bih0[grow] + bhh0[grow]) : 0.f;
        bw1[tt] = on ? (bih1[grow] + bhh1[grow]) : 0.f;
        #pragma unroll
        for (int s = 0; s < 2; ++s)
            #pragma unroll
            for (int j = 0; j < 8; ++j) {
                const int k = 32 * s + quad * 8 + j;
                float v = 0.f;
                if (on) {
                    if (k < Hn)           v = Whh0[grow * Hn + k];
                    else if (k < Hn + Dn) v = Wih0[grow * Dn + (k - Hn)];
                }
                short hi, lo; split_bf(v, hi, lo);
                B0[tt][s][0][j] = hi; B0[tt][s][1][j] = lo;
            }
        #pragma unroll
        for (int s = 0; s < 4; ++s)
            #pragma unroll
            for (int j = 0; j < 8; ++j) {
                const int k = 32 * s + quad * 8 + j;
                float v = 0.f;
                if (on) {
                    if (k < Hn)                      v = Wih1[grow * Hn + k];
                    else if (k >= 64 && k < 64 + Hn) v = Whh1[grow * Hn + (k - 64)];
                    // k 50..63: zero -> shared-pack x columns contribute 0
                }
                short hi, lo; split_bf(v, hi, lo);
                B1[tt][s][0][j] = hi; B1[tt][s][1][j] = lo;
            }
    }

    // ---- init: zero A-pack; stage x(0) into hi+lo rows ----
    for (int i = tid; i < 4 * 16 * 40; i += 512) aPS[i] = 0;
    __syncthreads();
    if (tid < 64) {
        const int xb = tid >> 3, xd = tid & 7;
        const float f = x[((size_t)(b0 + xb) * Tn + 0) * Dn + xd];
        short hi, lo; split_bf(f, hi, lo);
        aPS[(1 * 16 + xb) * 40 + 18 + xd]     = hi;
        aPS[(1 * 16 + 8 + xb) * 40 + 18 + xd] = lo;
    }
    __syncthreads();

    const int cA = tid >> 3, bA = tid & 7;   // act thread: cell 0..49, batch 0..7
    const bool actT = (tid < Hn * 8);        // 400 act threads (waves 0..6)
    float c0 = 0.f, c1 = 0.f;
    float xreg = 0.f;                        // wave-7 x staging register

    // ============ prologue: gates0(0) ; act0(0) ============
    if (ntw > 0) {
        f32x4 D0[2];
        #pragma unroll
        for (int tt = 0; tt < 2; ++tt) {
            const float z = (quad < 2) ? bw0[tt] : 0.f;   // bias only in hi rows
            f32x4 zi = {z, z, z, z}; D0[tt] = zi;
        }
        #pragma unroll
        for (int s = 0; s < 2; ++s) {
            const short8 a = *(const short8*)&aPS[(s * 16 + col) * 40 + quad * 8];
            #pragma unroll
            for (int tt = 0; tt < 2; ++tt)
                if (tt < ntw) {
                    D0[tt] = __builtin_amdgcn_mfma_f32_16x16x32_bf16(a, B0[tt][s][0], D0[tt], 0,0,0);
                    D0[tt] = __builtin_amdgcn_mfma_f32_16x16x32_bf16(a, B0[tt][s][1], D0[tt], 0,0,0);
                }
        }
        #pragma unroll
        for (int tt = 0; tt < 2; ++tt)
            if (tt < ntw) {
                const int n = (tb + tt) * 16 + col;
                #pragma unroll
                for (int r = 0; r < 4; ++r) gL[0][quad * 4 + r][n] = D0[tt][r];
            }
    } else {
        xreg = x[((size_t)(b0 + (lane >> 3)) * Tn + 1) * Dn + (lane & 7)];
    }
    __syncthreads();
    if (actT) {
        const f32x4 gm  = *(const f32x4*)&gL[0][bA][4 * cA];
        const f32x4 glo = *(const f32x4*)&gL[0][8 + bA][4 * cA];
        const float h = lstm_cell(gm, glo, c0);
        short hi, lo; split_bf(h, hi, lo);
        const int si = cA >> 5, k32 = cA & 31;
        aPS[(si * 16 + bA) * 40 + k32]     = hi;
        aPS[(si * 16 + 8 + bA) * 40 + k32] = lo;
    } else if (w == 7) {
        short hi, lo; split_bf(xreg, hi, lo);
        aPS[(1 * 16 + (lane >> 3)) * 40 + 18 + (lane & 7)]     = hi;
        aPS[(1 * 16 + 8 + (lane >> 3)) * 40 + 18 + (lane & 7)] = lo;
    }
    __syncthreads();

    // ============ main loop: t = 1 .. Tn-1 ============
    for (int t = 1; t < Tn; ++t) {
        // ---- phase M: gates0(t) + gates1(t-1), shared A-frags ----
        if (ntw > 0) {
            f32x4 D0[2], D1[2];
            #pragma unroll
            for (int tt = 0; tt < 2; ++tt) {
                const float z0 = (quad < 2) ? bw0[tt] : 0.f;
                const float z1 = (quad < 2) ? bw1[tt] : 0.f;
                f32x4 a0 = {z0, z0, z0, z0}; D0[tt] = a0;
                f32x4 a1 = {z1, z1, z1, z1}; D1[tt] = a1;
            }
            #pragma unroll
            for (int s = 0; s < 2; ++s) {       // shared [h0|x] ksteps
                const short8 a = *(const short8*)&aPS[(s * 16 + col) * 40 + quad * 8];
                #pragma unroll
                for (int tt = 0; tt < 2; ++tt)
                    if (tt < ntw) {
                        D0[tt] = __builtin_amdgcn_mfma_f32_16x16x32_bf16(a, B0[tt][s][0], D0[tt], 0,0,0);
                        D0[tt] = __builtin_amdgcn_mfma_f32_16x16x32_bf16(a, B0[tt][s][1], D0[tt], 0,0,0);
                        D1[tt] = __builtin_amdgcn_mfma_f32_16x16x32_bf16(a, B1[tt][s][0], D1[tt], 0,0,0);
                        D1[tt] = __builtin_amdgcn_mfma_f32_16x16x32_bf16(a, B1[tt][s][1], D1[tt], 0,0,0);
                    }
            }
            #pragma unroll
            for (int s = 2; s < 4; ++s) {       // h1 ksteps
                const short8 a = *(const short8*)&aPS[(s * 16 + col) * 40 + quad * 8];
                #pragma unroll
                for (int tt = 0; tt < 2; ++tt)
                    if (tt < ntw) {
                        D1[tt] = __builtin_amdgcn_mfma_f32_16x16x32_bf16(a, B1[tt][s][0], D1[tt], 0,0,0);
                        D1[tt] = __builtin_amdgcn_mfma_f32_16x16x32_bf16(a, B1[tt][s][1], D1[tt], 0,0,0);
                    }
            }
            #pragma unroll
            for (int tt = 0; tt < 2; ++tt)
                if (tt < ntw) {
                    const int n = (tb + tt) * 16 + col;
                    #pragma unroll
                    for (int r = 0; r < 4; ++r) {
                        gL[0][quad * 4 + r][n] = D0[tt][r];
                        gL[1][quad * 4 + r][n] = D1[tt][r];
                    }
                }
        } else {
            const int tn = (t + 1 < Tn) ? (t + 1) : (Tn - 1);
            xreg = x[((size_t)(b0 + (lane >> 3)) * Tn + tn) * Dn + (lane & 7)];
        }
        __syncthreads();

        // ---- phase A: act1(t-1) then act0(t); wave 7 stages x(t+1) ----
        if (actT) {
            {   // layer-1 activation for step t-1 -> h1 region (s2,s3)
                const f32x4 gm  = *(const f32x4*)&gL[1][bA][4 * cA];
                const f32x4 glo = *(const f32x4*)&gL[1][8 + bA][4 * cA];
                const float h = lstm_cell(gm, glo, c1);
                short hi, lo; split_bf(h, hi, lo);
                const int si = 2 + (cA >> 5), k32 = cA & 31;
                aPS[(si * 16 + bA) * 40 + k32]     = hi;
                aPS[(si * 16 + 8 + bA) * 40 + k32] = lo;
            }
            {   // layer-0 activation for step t -> shared region (s0,s1)
                const f32x4 gm  = *(const f32x4*)&gL[0][bA][4 * cA];
                const f32x4 glo = *(const f32x4*)&gL[0][8 + bA][4 * cA];
                const float h = lstm_cell(gm, glo, c0);
                short hi, lo; split_bf(h, hi, lo);
                const int si = cA >> 5, k32 = cA & 31;
                aPS[(si * 16 + bA) * 40 + k32]     = hi;
                aPS[(si * 16 + 8 + bA) * 40 + k32] = lo;
            }
        } else if (w == 7) {
            short hi, lo; split_bf(xreg, hi, lo);
            aPS[(1 * 16 + (lane >> 3)) * 40 + 18 + (lane & 7)]     = hi;
            aPS[(1 * 16 + 8 + (lane >> 3)) * 40 + 18 + (lane & 7)] = lo;
        }
        __syncthreads();
    }

    // ============ epilogue: gates1(Tn-1) ; act1(Tn-1) ============
    if (ntw > 0) {
        f32x4 D1[2];
        #pragma unroll
        for (int tt = 0; tt < 2; ++tt) {
            const float z = (quad < 2) ? bw1[tt] : 0.f;
            f32x4 zi = {z, z, z, z}; D1[tt] = zi;
        }
        #pragma unroll
        for (int s = 0; s < 4; ++s) {
            const short8 a = *(const short8*)&aPS[(s * 16 + col) * 40 + quad * 8];
            #pragma unroll
            for (int tt = 0; tt < 2; ++tt)
                if (tt < ntw) {
                    D1[tt] = __builtin_amdgcn_mfma_f32_16x16x32_bf16(a, B1[tt][s][0], D1[tt], 0,0,0);
                    D1[tt] = __builtin_amdgcn_mfma_f32_16x16x32_bf16(a, B1[tt][s][1], D1[tt], 0,0,0);
                }
        }
        #pragma unroll
        for (int tt = 0; tt < 2; ++tt)
            if (tt < ntw) {
                const int n = (tb + tt) * 16 + col;
                #pragma unroll
                for (int r = 0; r < 4; ++r) gL[1][quad * 4 + r][n] = D1[tt][r];
            }
    }
    __syncthreads();
    if (actT) {
        const f32x4 gm  = *(const f32x4*)&gL[1][bA][4 * cA];
        const f32x4 glo = *(const f32x4*)&gL[1][8 + bA][4 * cA];
        const float h = lstm_cell(gm, glo, c1);
        h1f[cA * BB + bA] = h;
    }
    __syncthreads();

    // ---- head: out[b] = h1_last . Wlin + blin (fp32 path) ----
    if (tid < BB) {
        float o = blin[0];
        #pragma unroll
        for (int k = 0; k < Hn; ++k) o += Wlin[k] * h1f[k * BB + tid];
        out[b0 + tid] = o;
    }
}

extern "C" void kernel_launch(void* const* d_in, const int* in_sizes, int n_in,
                              void* d_out, int out_size, void* d_ws, size_t ws_size,
                              hipStream_t stream) {
    const float* x    = (const float*)d_in[0];
    const float* Wih0 = (const float*)d_in[1];
    const float* Whh0 = (const float*)d_in[2];
    const float* bih0 = (const float*)d_in[3];
    const float* bhh0 = (const float*)d_in[4];
    const float* Wih1 = (const float*)d_in[5];
    const float* Whh1 = (const float*)d_in[6];
    const float* bih1 = (const float*)d_in[7];
    const float* bhh1 = (const float*)d_in[8];
    const float* Wlin = (const float*)d_in[9];
    const float* blin = (const float*)d_in[10];
    float* out = (float*)d_out;

    lstm2_kernel<<<NBLK, 512, 0, stream>>>(x, Wih0, Whh0, bih0, bhh0,
                                           Wih1, Whh1, bih1, bhh1,
                                           Wlin, blin, out);
}

// Round 3
// 476.238 us; speedup vs baseline: 2.4504x; 1.3272x over previous
//
#include <hip/hip_runtime.h>
#include <math.h>

#define Hn 50
#define Dn 8
#define Tn 512
#define BB 8               // batches per block
#define NBLK 256           // 2048/8 -> 1 block/CU
#define KST 136            // bP row stride (shorts): 128 + 8 pad -> 4-bank row skew

typedef __attribute__((ext_vector_type(8))) short short8;   // 8 bf16 (4 VGPRs)
typedef __attribute__((ext_vector_type(4))) float f32x4;

__device__ __forceinline__ float fexp2_(float x) {
#if __has_builtin(__builtin_amdgcn_exp2f)
    return __builtin_amdgcn_exp2f(x);
#else
    return exp2f(x);
#endif
}
__device__ __forceinline__ float frcp_(float x) {
#if __has_builtin(__builtin_amdgcn_rcpf)
    return __builtin_amdgcn_rcpf(x);
#else
    return 1.0f / x;
#endif
}
__device__ __forceinline__ float sigmoidf_(float x) {
    return frcp_(1.0f + fexp2_(-1.44269504f * x));
}
__device__ __forceinline__ float tanhf_(float x) {
    return 2.0f * sigmoidf_(2.0f * x) - 1.0f;
}
__device__ __forceinline__ float bf2f(short s) {
    return __uint_as_float(((unsigned)(unsigned short)s) << 16);
}
// truncation split: v = hi + lo + O(2^-17 v)
__device__ __forceinline__ void split_bf(float v, short& hi, short& lo) {
    hi = (short)(__float_as_uint(v) >> 16);
    const float r = v - bf2f(hi);
    lo = (short)(__float_as_uint(r) >> 16);
}
// in-register LSTM cell: g4 = (i,f,g,o) pre-activation, c = cell state
__device__ __forceinline__ float lstm_cell4(const f32x4 g4, float& c) {
    c = sigmoidf_(g4.y) * c + sigmoidf_(g4.x) * tanhf_(g4.z);
    return sigmoidf_(g4.w) * tanhf_(c);
}
__device__ __forceinline__ float shflxor8(float v) {
    return __shfl_xor(v, 8, 64);
}

// ============================================================================
// r15: TRANSPOSED persistent 2-layer LSTM — gates in M, batch in N.
//   D = W_frag (A: M=16 gate rows, K=32) x h_frag (B: K=32, N=16)
//   B cols 0..7 = h_hi of batches 0..7, cols 8..15 = h_lo.
//   Two MFMAs per (slot,kstep): W_hi and W_lo into ONE acc; lane b + lane b+8
//   summed via shfl_xor(8) -> all 4 precision cross terms kept.
//   C/D layout: n=lane&15 (batch/half), m=(lane>>4)*4+reg -> lane's 4 regs are
//   the (i,f,g,o) of cell 4T+quad -> act runs IN-REGISTER. No gate LDS buffer,
//   ONE barrier per timestep (r12-r14 had two + a 33KB gL round-trip).
// K layout (shared between layers): k 0..49 = h0 | 50..57 = x | 64..113 = h1.
//   L0 slots use ksteps 0,1 (W=Whh0|Wih0); L1 slots use ksteps 0..3
//   (W=Wih1 at k<50, 0 at 50..63, Whh1 at 64..113).
// Double-buffered h-pack bP[2][n=16][k=KST]; phase t reads bP[t&1], writes
//   bP[(t+1)&1]. One barrier/phase is race-free: a wave can't be 2 phases
//   ahead without all waves passing the intervening barrier.
// Wave shapes (26 gate-tiles over 8 waves, ~20 MFMA each):
//   w0..5: 1 L0 (tile w) + 2 L1 (tiles 2w,2w+1)   -> 20 MFMA
//   w6   : 4 L0 (tiles 6..9) + x(t+1) staging      -> 16 MFMA
//   w7   : 3 L0 (tiles 10..12) + 1 L1 (tile 12)    -> 20 MFMA
// Barrier counts identical across shapes (512 in-loop + pro/epilogue).
// ============================================================================

template<int NL1, int NL0, bool XD>
__device__ __forceinline__ void run_loop(
    const int* l1T, const int* l0T,
    int b0, int lane, int quad, int col,
    short (*bP)[16][KST], float* h1f, const float* x,
    const float* Wih0, const float* Whh0, const float* bih0, const float* bhh0,
    const float* Wih1, const float* Whh1, const float* bih1, const float* bhh1)
{
    constexpr int NS = NL1 + NL0;
    constexpr int NPAIR = (NS + 1) / 2;
    constexpr int NBF = (NL1 > 0) ? 4 : 2;

    short8 W1[NL1 > 0 ? NL1 : 1][4][2];   // [slot][kstep][hi/lo]
    short8 W0[NL0 > 0 ? NL0 : 1][2][2];
    float  bias[NS][4];
    int    kb[NS];      // k index base for h-write: layer*64 + 4*T
    int    cellb[NS];   // cell base: 4*T

    // ---- stationary A-side weights: lane holds W[m=col][k=32s+quad*8+j] ----
    #pragma unroll
    for (int i = 0; i < NL1; ++i) {
        const int T = l1T[i];
        const int ng = T * 16 + col, cl = ng >> 2, g = ng & 3;
        const bool on = (cl < Hn);
        const int grow = g * Hn + cl;
        #pragma unroll
        for (int s = 0; s < 4; ++s)
            #pragma unroll
            for (int j = 0; j < 8; ++j) {
                const int k = 32 * s + quad * 8 + j;
                float v = 0.f;
                if (on) {
                    if (k < Hn)                      v = Wih1[grow * Hn + k];
                    else if (k >= 64 && k < 64 + Hn) v = Whh1[grow * Hn + (k - 64)];
                }
                short hi, lo; split_bf(v, hi, lo);
                W1[i][s][0][j] = hi; W1[i][s][1][j] = lo;
            }
        const int myc = 4 * T + quad;
        #pragma unroll
        for (int r = 0; r < 4; ++r)
            bias[i][r] = (myc < Hn) ? (bih1[r * Hn + myc] + bhh1[r * Hn + myc]) : 0.f;
        kb[i] = 64 + 4 * T; cellb[i] = 4 * T;
    }
    #pragma unroll
    for (int i = 0; i < NL0; ++i) {
        const int T = l0T[i];
        const int ng = T * 16 + col, cl = ng >> 2, g = ng & 3;
        const bool on = (cl < Hn);
        const int grow = g * Hn + cl;
        #pragma unroll
        for (int s = 0; s < 2; ++s)
            #pragma unroll
            for (int j = 0; j < 8; ++j) {
                const int k = 32 * s + quad * 8 + j;
                float v = 0.f;
                if (on) {
                    if (k < Hn)           v = Whh0[grow * Hn + k];
                    else if (k < Hn + Dn) v = Wih0[grow * Dn + (k - Hn)];
                }
                short hi, lo; split_bf(v, hi, lo);
                W0[i][s][0][j] = hi; W0[i][s][1][j] = lo;
            }
        const int myc = 4 * T + quad;
        #pragma unroll
        for (int r = 0; r < 4; ++r)
            bias[NL1 + i][r] = (myc < Hn) ? (bih0[r * Hn + myc] + bhh0[r * Hn + myc]) : 0.f;
        kb[NL1 + i] = 4 * T; cellb[NL1 + i] = 4 * T;
    }

    float c[NPAIR];
    #pragma unroll
    for (int p = 0; p < NPAIR; ++p) c[p] = 0.f;

    const float* xp = XD ? (x + (size_t)(b0 + (lane >> 3)) * Tn * Dn + (lane & 7))
                         : (const float*)nullptr;

    // ================= main loop: one phase (one barrier) per timestep ======
    for (int t = 0; t < Tn; ++t) {
        float xv = 0.f;
        if (XD) { if (t + 1 < Tn) xv = xp[(size_t)(t + 1) * Dn]; }   // issue early

        const short (*bR)[KST] = (const short (*)[KST])bP[t & 1];
        short (*bW)[KST] = bP[(t + 1) & 1];

        // B-side fragments: lane reads h[k=32s+quad*8 .. +7] for its n=col
        short8 BF[NBF];
        #pragma unroll
        for (int s = 0; s < NBF; ++s)
            BF[s] = *(const short8*)&bR[col][32 * s + quad * 8];

        f32x4 acc[NS];
        #pragma unroll
        for (int i = 0; i < NS; ++i) {
            #pragma unroll
            for (int r = 0; r < 4; ++r) acc[i][r] = (col < 8) ? bias[i][r] : 0.f;
        }
        #pragma unroll
        for (int i = 0; i < NL1; ++i)
            #pragma unroll
            for (int s = 0; s < 4; ++s) {
                acc[i] = __builtin_amdgcn_mfma_f32_16x16x32_bf16(W1[i][s][0], BF[s], acc[i], 0, 0, 0);
                acc[i] = __builtin_amdgcn_mfma_f32_16x16x32_bf16(W1[i][s][1], BF[s], acc[i], 0, 0, 0);
            }
        #pragma unroll
        for (int i = 0; i < NL0; ++i)
            #pragma unroll
            for (int s = 0; s < 2; ++s) {
                acc[NL1 + i] = __builtin_amdgcn_mfma_f32_16x16x32_bf16(W0[i][s][0], BF[s], acc[NL1 + i], 0, 0, 0);
                acc[NL1 + i] = __builtin_amdgcn_mfma_f32_16x16x32_bf16(W0[i][s][1], BF[s], acc[NL1 + i], 0, 0, 0);
            }

        // ---- in-register act: pair slots so col<8 / col>=8 halves act on
        //      different slots (no redundant transcendental work) ----
        #pragma unroll
        for (int p = 0; p < NPAIR; ++p) {
            const int ia = 2 * p;
            const bool hasB  = (ia + 1 < NS);
            const bool isL1a = (ia < NL1);
            const bool isL1b = (ia + 1 < NL1);
            f32x4 g;
            #pragma unroll
            for (int r = 0; r < 4; ++r) {
                const float sa = acc[ia][r] + shflxor8(acc[ia][r]);
                float sel = sa;
                if (hasB) {
                    const float sb = acc[ia + 1][r] + shflxor8(acc[ia + 1][r]);
                    sel = (col < 8) ? sa : sb;
                }
                g[r] = sel;
            }
            int cell, kc; bool isl1;
            if (hasB && col >= 8) { cell = cellb[ia + 1] + quad; kc = kb[ia + 1] + quad; isl1 = isL1b; }
            else                  { cell = cellb[ia] + quad;     kc = kb[ia] + quad;     isl1 = isL1a; }
            const bool doAct = (cell < Hn) && ((t >= 1) || !isl1);   // L1 lags one step
            if (doAct) {
                const float h = lstm_cell4(g, c[p]);
                short hi, lo; split_bf(h, hi, lo);
                if (hasB) { bW[col & 7][kc] = hi; bW[(col & 7) + 8][kc] = lo; }
                else      { bW[col][kc] = (col < 8) ? hi : lo; }
            }
        }
        if (XD) {
            if (t + 1 < Tn) {
                short hi, lo; split_bf(xv, hi, lo);
                bW[lane >> 3][Hn + (lane & 7)]       = hi;
                bW[(lane >> 3) + 8][Hn + (lane & 7)] = lo;
            }
        }
        __syncthreads();
    }

    // ======== epilogue phase: gates1(Tn-1) + act1 -> h1f (fp32) ========
    if constexpr (NL1 > 0) {
        const short (*bR)[KST] = (const short (*)[KST])bP[Tn & 1];
        short8 BF[4];
        #pragma unroll
        for (int s = 0; s < 4; ++s)
            BF[s] = *(const short8*)&bR[col][32 * s + quad * 8];
        f32x4 accE[NL1];
        #pragma unroll
        for (int i = 0; i < NL1; ++i) {
            #pragma unroll
            for (int r = 0; r < 4; ++r) accE[i][r] = (col < 8) ? bias[i][r] : 0.f;
        }
        #pragma unroll
        for (int i = 0; i < NL1; ++i)
            #pragma unroll
            for (int s = 0; s < 4; ++s) {
                accE[i] = __builtin_amdgcn_mfma_f32_16x16x32_bf16(W1[i][s][0], BF[s], accE[i], 0, 0, 0);
                accE[i] = __builtin_amdgcn_mfma_f32_16x16x32_bf16(W1[i][s][1], BF[s], accE[i], 0, 0, 0);
            }
        #pragma unroll
        for (int p = 0; p < NPAIR; ++p) {
            const int ia = 2 * p;
            if (ia < NL1) {
                const bool bL1 = (ia + 1 < NL1);
                f32x4 g;
                #pragma unroll
                for (int r = 0; r < 4; ++r) {
                    const float sa = accE[ia][r] + shflxor8(accE[ia][r]);
                    float sel = sa;
                    if (bL1) {
                        const float sb = accE[ia + 1][r] + shflxor8(accE[ia + 1][r]);
                        sel = (col < 8) ? sa : sb;
                    }
                    g[r] = sel;
                }
                int cell; bool mine;
                if (bL1) { cell = ((col < 8) ? cellb[ia] : cellb[ia + 1]) + quad; mine = true; }
                else     { cell = cellb[ia] + quad;                               mine = (col < 8); }
                if (mine && cell < Hn) {
                    const float h = lstm_cell4(g, c[p]);
                    h1f[cell * 8 + (col & 7)] = h;
                }
            }
        }
    }
}

__global__ __launch_bounds__(512, 1) void lstm2_kernel(
    const float* __restrict__ x,
    const float* __restrict__ Wih0, const float* __restrict__ Whh0,
    const float* __restrict__ bih0, const float* __restrict__ bhh0,
    const float* __restrict__ Wih1, const float* __restrict__ Whh1,
    const float* __restrict__ bih1, const float* __restrict__ bhh1,
    const float* __restrict__ Wlin, const float* __restrict__ blin,
    float* __restrict__ out)
{
    const int tid  = threadIdx.x;     // 0..511
    const int b0   = blockIdx.x * BB;
    // readfirstlane: wave index must be SGPR-uniform so the shape dispatch is a
    // scalar branch — __syncthreads lives inside the branches.
    const int w    = __builtin_amdgcn_readfirstlane(tid >> 6);
    const int lane = tid & 63;
    const int quad = lane >> 4;
    const int col  = lane & 15;

    __shared__ __align__(16) short bP[2][16][KST];   // double-buffered h/x pack
    __shared__ float h1f[Hn * 8];                    // fp32 h1 at t=Tn-1

    // ---- init: zero both buffers (initial h0/h1 = 0); stage x(0) ----
    for (int i = tid; i < 2 * 16 * KST; i += 512) (&bP[0][0][0])[i] = 0;
    __syncthreads();
    if (tid < 64) {
        const int xb = tid >> 3, xd = tid & 7;
        const float f = x[((size_t)(b0 + xb) * Tn + 0) * Dn + xd];
        short hi, lo; split_bf(f, hi, lo);
        bP[0][xb][Hn + xd]     = hi;
        bP[0][xb + 8][Hn + xd] = lo;
    }
    __syncthreads();

    if (w < 6) {
        const int l1t[2] = {2 * w, 2 * w + 1};
        const int l0t[1] = {w};
        run_loop<2, 1, false>(l1t, l0t, b0, lane, quad, col, bP, h1f, x,
                              Wih0, Whh0, bih0, bhh0, Wih1, Whh1, bih1, bhh1);
    } else if (w == 6) {
        const int l1t[1] = {0};
        const int l0t[4] = {6, 7, 8, 9};
        run_loop<0, 4, true>(l1t, l0t, b0, lane, quad, col, bP, h1f, x,
                             Wih0, Whh0, bih0, bhh0, Wih1, Whh1, bih1, bhh1);
    } else {
        const int l1t[1] = {12};
        const int l0t[3] = {10, 11, 12};
        run_loop<1, 3, false>(l1t, l0t, b0, lane, quad, col, bP, h1f, x,
                              Wih0, Whh0, bih0, bhh0, Wih1, Whh1, bih1, bhh1);
    }
    __syncthreads();

    // ---- head: out[b] = h1_last . Wlin + blin (fp32 path) ----
    if (tid < BB) {
        float o = blin[0];
        #pragma unroll
        for (int k = 0; k < Hn; ++k) o += Wlin[k] * h1f[k * 8 + tid];
        out[b0 + tid] = o;
    }
}

extern "C" void kernel_launch(void* const* d_in, const int* in_sizes, int n_in,
                              void* d_out, int out_size, void* d_ws, size_t ws_size,
                              hipStream_t stream) {
    const float* x    = (const float*)d_in[0];
    const float* Wih0 = (const float*)d_in[1];
    const float* Whh0 = (const float*)d_in[2];
    const float* bih0 = (const float*)d_in[3];
    const float* bhh0 = (const float*)d_in[4];
    const float* Wih1 = (const float*)d_in[5];
    const float* Whh1 = (const float*)d_in[6];
    const float* bih1 = (const float*)d_in[7];
    const float* bhh1 = (const float*)d_in[8];
    const float* Wlin = (const float*)d_in[9];
    const float* blin = (const float*)d_in[10];
    float* out = (float*)d_out;

    lstm2_kernel<<<NBLK, 512, 0, stream>>>(x, Wih0, Whh0, bih0, bhh0,
                                           Wih1, Whh1, bih1, bhh1,
                                           Wlin, blin, out);
}

// Round 4
// 471.117 us; speedup vs baseline: 2.4770x; 1.0109x over previous
//
#include <hip/hip_runtime.h>
#include <math.h>

#define Hn 50
#define Dn 8
#define Tn 512
#define BB 8               // batches per block
#define NBLK 256           // 2048/8 -> 1 block/CU
#define KST 136            // bP row stride (shorts): 128 + 8 pad

typedef __attribute__((ext_vector_type(8))) short short8;   // 8 bf16 (4 VGPRs)
typedef __attribute__((ext_vector_type(4))) float f32x4;

__device__ __forceinline__ float fexp2_(float x) {
#if __has_builtin(__builtin_amdgcn_exp2f)
    return __builtin_amdgcn_exp2f(x);
#else
    return exp2f(x);
#endif
}
__device__ __forceinline__ float frcp_(float x) {
#if __has_builtin(__builtin_amdgcn_rcpf)
    return __builtin_amdgcn_rcpf(x);
#else
    return 1.0f / x;
#endif
}
__device__ __forceinline__ float sigmoidf_(float x) {
    return frcp_(1.0f + fexp2_(-1.44269504f * x));
}
__device__ __forceinline__ float tanhf_(float x) {
    return 2.0f * sigmoidf_(2.0f * x) - 1.0f;
}
__device__ __forceinline__ float bf2f(short s) {
    return __uint_as_float(((unsigned)(unsigned short)s) << 16);
}
// truncation split: v = hi + lo + O(2^-17 v)
__device__ __forceinline__ void split_bf(float v, short& hi, short& lo) {
    hi = (short)(__float_as_uint(v) >> 16);
    const float r = v - bf2f(hi);
    lo = (short)(__float_as_uint(r) >> 16);
}
// in-register LSTM cell: g4 = (i,f,g,o) pre-activation, c = cell state
__device__ __forceinline__ float lstm_cell4(const f32x4 g4, float& c) {
    c = sigmoidf_(g4.y) * c + sigmoidf_(g4.x) * tanhf_(g4.z);
    return sigmoidf_(g4.w) * tanhf_(c);
}
__device__ __forceinline__ float shflxor8(float v) {
    return __shfl_xor(v, 8, 64);
}

// ============================================================================
// r16: r15's transposed design + LAYER-SPECIALIZED WAVES.
// r15 post-mortem: 2176 cy/step = MFMA 776 (40 x 19.4 cy/SIMD) + VALU 1110,
// additive -> pipes not overlapping because every wave ran the same
// [MFMA burst | act burst] schedule in barrier lockstep.
// r16: waves 0-3 own all 13 L0 tiles (12-16 MFMA, 4-deep chains); waves 4-7
// own all 13 L1 tiles (24-32 MFMA, 8-deep). SIMD i hosts wave i (L0) + wave
// i+4 (L1): the L0 wave exits its short MFMA burst early and runs its
// transcendental act under the L1 wave's MFMA window (m114: MFMA+VALU
// co-issue across waves). Also: u/v shuffle merge halves ds_bpermute count
// (g = sel(a,b) + shflxor8(sel(b,a)) -- one shfl per reg instead of two).
// Everything else identical to r15 (layouts, lag-1 L1, one barrier/step).
// K layout: k 0..49 = h0 | 50..57 = x | 64..113 = h1.
// C/D: n=lane&15 (batch: cols 0..7 hi, 8..15 lo), m=(lane>>4)*4+reg = the
// (i,f,g,o) of cell 4T+quad -> act fully in-register.
// ============================================================================

template<int NL1, int NL0, bool XD>
__device__ __forceinline__ void run_loop(
    const int* l1T, const int* l0T,
    int b0, int lane, int quad, int col,
    short (*bP)[16][KST], float* h1f, const float* x,
    const float* Wih0, const float* Whh0, const float* bih0, const float* bhh0,
    const float* Wih1, const float* Whh1, const float* bih1, const float* bhh1)
{
    constexpr int NS = NL1 + NL0;
    constexpr int NPAIR = (NS + 1) / 2;
    constexpr int NBF = (NL1 > 0) ? 4 : 2;

    short8 W1[NL1 > 0 ? NL1 : 1][4][2];   // [slot][kstep][hi/lo]
    short8 W0[NL0 > 0 ? NL0 : 1][2][2];
    float  bias[NS][4];
    int    kb[NS];      // k index base for h-write: layer*64 + 4*T
    int    cellb[NS];   // cell base: 4*T

    // ---- stationary A-side weights: lane holds W[m=col][k=32s+quad*8+j] ----
    #pragma unroll
    for (int i = 0; i < NL1; ++i) {
        const int T = l1T[i];
        const int ng = T * 16 + col, cl = ng >> 2, g = ng & 3;
        const bool on = (cl < Hn);
        const int grow = g * Hn + cl;
        #pragma unroll
        for (int s = 0; s < 4; ++s)
            #pragma unroll
            for (int j = 0; j < 8; ++j) {
                const int k = 32 * s + quad * 8 + j;
                float v = 0.f;
                if (on) {
                    if (k < Hn)                      v = Wih1[grow * Hn + k];
                    else if (k >= 64 && k < 64 + Hn) v = Whh1[grow * Hn + (k - 64)];
                }
                short hi, lo; split_bf(v, hi, lo);
                W1[i][s][0][j] = hi; W1[i][s][1][j] = lo;
            }
        const int myc = 4 * T + quad;
        #pragma unroll
        for (int r = 0; r < 4; ++r)
            bias[i][r] = (myc < Hn) ? (bih1[r * Hn + myc] + bhh1[r * Hn + myc]) : 0.f;
        kb[i] = 64 + 4 * T; cellb[i] = 4 * T;
    }
    #pragma unroll
    for (int i = 0; i < NL0; ++i) {
        const int T = l0T[i];
        const int ng = T * 16 + col, cl = ng >> 2, g = ng & 3;
        const bool on = (cl < Hn);
        const int grow = g * Hn + cl;
        #pragma unroll
        for (int s = 0; s < 2; ++s)
            #pragma unroll
            for (int j = 0; j < 8; ++j) {
                const int k = 32 * s + quad * 8 + j;
                float v = 0.f;
                if (on) {
                    if (k < Hn)           v = Whh0[grow * Hn + k];
                    else if (k < Hn + Dn) v = Wih0[grow * Dn + (k - Hn)];
                }
                short hi, lo; split_bf(v, hi, lo);
                W0[i][s][0][j] = hi; W0[i][s][1][j] = lo;
            }
        const int myc = 4 * T + quad;
        #pragma unroll
        for (int r = 0; r < 4; ++r)
            bias[NL1 + i][r] = (myc < Hn) ? (bih0[r * Hn + myc] + bhh0[r * Hn + myc]) : 0.f;
        kb[NL1 + i] = 4 * T; cellb[NL1 + i] = 4 * T;
    }

    float c[NPAIR];
    #pragma unroll
    for (int p = 0; p < NPAIR; ++p) c[p] = 0.f;

    const float* xp = XD ? (x + (size_t)(b0 + (lane >> 3)) * Tn * Dn + (lane & 7))
                         : (const float*)nullptr;

    // ================= main loop: one phase (one barrier) per timestep ======
    for (int t = 0; t < Tn; ++t) {
        float xv = 0.f;
        if (XD) { if (t + 1 < Tn) xv = xp[(size_t)(t + 1) * Dn]; }   // issue early

        const short (*bR)[KST] = (const short (*)[KST])bP[t & 1];
        short (*bW)[KST] = bP[(t + 1) & 1];

        // B-side fragments: lane reads h[k=32s+quad*8 .. +7] for its n=col
        short8 BF[NBF];
        #pragma unroll
        for (int s = 0; s < NBF; ++s)
            BF[s] = *(const short8*)&bR[col][32 * s + quad * 8];

        f32x4 acc[NS];
        #pragma unroll
        for (int i = 0; i < NS; ++i) {
            #pragma unroll
            for (int r = 0; r < 4; ++r) acc[i][r] = (col < 8) ? bias[i][r] : 0.f;
        }
        #pragma unroll
        for (int i = 0; i < NL1; ++i)
            #pragma unroll
            for (int s = 0; s < 4; ++s) {
                acc[i] = __builtin_amdgcn_mfma_f32_16x16x32_bf16(W1[i][s][0], BF[s], acc[i], 0, 0, 0);
                acc[i] = __builtin_amdgcn_mfma_f32_16x16x32_bf16(W1[i][s][1], BF[s], acc[i], 0, 0, 0);
            }
        #pragma unroll
        for (int i = 0; i < NL0; ++i)
            #pragma unroll
            for (int s = 0; s < 2; ++s) {
                acc[NL1 + i] = __builtin_amdgcn_mfma_f32_16x16x32_bf16(W0[i][s][0], BF[s], acc[NL1 + i], 0, 0, 0);
                acc[NL1 + i] = __builtin_amdgcn_mfma_f32_16x16x32_bf16(W0[i][s][1], BF[s], acc[NL1 + i], 0, 0, 0);
            }

        // ---- in-register act: paired slots, u/v single-shfl merge ----
        #pragma unroll
        for (int p = 0; p < NPAIR; ++p) {
            const int ia = 2 * p;
            const bool hasB  = (ia + 1 < NS);
            const bool isL1a = (ia < NL1);
            const bool isL1b = (ia + 1 < NL1);
            f32x4 g;
            #pragma unroll
            for (int r = 0; r < 4; ++r) {
                if (hasB) {
                    const float u = (col < 8) ? acc[ia][r]     : acc[ia + 1][r];
                    const float v = (col < 8) ? acc[ia + 1][r] : acc[ia][r];
                    g[r] = u + shflxor8(v);
                } else {
                    g[r] = acc[ia][r] + shflxor8(acc[ia][r]);
                }
            }
            int cell, kc; bool isl1;
            if (hasB && col >= 8) { cell = cellb[ia + 1] + quad; kc = kb[ia + 1] + quad; isl1 = isL1b; }
            else                  { cell = cellb[ia] + quad;     kc = kb[ia] + quad;     isl1 = isL1a; }
            const bool doAct = (cell < Hn) && ((t >= 1) || !isl1);   // L1 lags one step
            if (doAct) {
                const float h = lstm_cell4(g, c[p]);
                short hi, lo; split_bf(h, hi, lo);
                if (hasB) { bW[col & 7][kc] = hi; bW[(col & 7) + 8][kc] = lo; }
                else      { bW[col][kc] = (col < 8) ? hi : lo; }
            }
        }
        if (XD) {
            if (t + 1 < Tn) {
                short hi, lo; split_bf(xv, hi, lo);
                bW[lane >> 3][Hn + (lane & 7)]       = hi;
                bW[(lane >> 3) + 8][Hn + (lane & 7)] = lo;
            }
        }
        __syncthreads();
    }

    // ======== epilogue phase: gates1(Tn-1) + act1 -> h1f (fp32) ========
    if constexpr (NL1 > 0) {
        const short (*bR)[KST] = (const short (*)[KST])bP[Tn & 1];
        short8 BF[4];
        #pragma unroll
        for (int s = 0; s < 4; ++s)
            BF[s] = *(const short8*)&bR[col][32 * s + quad * 8];
        f32x4 accE[NL1];
        #pragma unroll
        for (int i = 0; i < NL1; ++i) {
            #pragma unroll
            for (int r = 0; r < 4; ++r) accE[i][r] = (col < 8) ? bias[i][r] : 0.f;
        }
        #pragma unroll
        for (int i = 0; i < NL1; ++i)
            #pragma unroll
            for (int s = 0; s < 4; ++s) {
                accE[i] = __builtin_amdgcn_mfma_f32_16x16x32_bf16(W1[i][s][0], BF[s], accE[i], 0, 0, 0);
                accE[i] = __builtin_amdgcn_mfma_f32_16x16x32_bf16(W1[i][s][1], BF[s], accE[i], 0, 0, 0);
            }
        #pragma unroll
        for (int p = 0; p < NPAIR; ++p) {
            const int ia = 2 * p;
            if (ia < NL1) {
                const bool bL1 = (ia + 1 < NL1);
                f32x4 g;
                #pragma unroll
                for (int r = 0; r < 4; ++r) {
                    if (bL1) {
                        const float u = (col < 8) ? accE[ia][r]     : accE[ia + 1][r];
                        const float v = (col < 8) ? accE[ia + 1][r] : accE[ia][r];
                        g[r] = u + shflxor8(v);
                    } else {
                        g[r] = accE[ia][r] + shflxor8(accE[ia][r]);
                    }
                }
                int cell; bool mine;
                if (bL1) { cell = ((col < 8) ? cellb[ia] : cellb[ia + 1]) + quad; mine = true; }
                else     { cell = cellb[ia] + quad;                               mine = (col < 8); }
                if (mine && cell < Hn) {
                    const float h = lstm_cell4(g, c[p]);
                    h1f[cell * 8 + (col & 7)] = h;
                }
            }
        }
    }
}

__global__ __launch_bounds__(512, 2) void lstm2_kernel(
    const float* __restrict__ x,
    const float* __restrict__ Wih0, const float* __restrict__ Whh0,
    const float* __restrict__ bih0, const float* __restrict__ bhh0,
    const float* __restrict__ Wih1, const float* __restrict__ Whh1,
    const float* __restrict__ bih1, const float* __restrict__ bhh1,
    const float* __restrict__ Wlin, const float* __restrict__ blin,
    float* __restrict__ out)
{
    const int tid  = threadIdx.x;     // 0..511
    const int b0   = blockIdx.x * BB;
    // readfirstlane: wave index SGPR-uniform so shape dispatch is scalar —
    // __syncthreads lives inside the branches (equal counts in all arms).
    const int w    = __builtin_amdgcn_readfirstlane(tid >> 6);
    const int lane = tid & 63;
    const int quad = lane >> 4;
    const int col  = lane & 15;

    __shared__ __align__(16) short bP[2][16][KST];   // double-buffered h/x pack
    __shared__ float h1f[Hn * 8];                    // fp32 h1 at t=Tn-1

    // ---- init: zero both buffers (initial h0/h1 = 0); stage x(0) ----
    for (int i = tid; i < 2 * 16 * KST; i += 512) (&bP[0][0][0])[i] = 0;
    __syncthreads();
    if (tid < 64) {
        const int xb = tid >> 3, xd = tid & 7;
        const float f = x[((size_t)(b0 + xb) * Tn + 0) * Dn + xd];
        short hi, lo; split_bf(f, hi, lo);
        bP[0][xb][Hn + xd]     = hi;
        bP[0][xb + 8][Hn + xd] = lo;
    }
    __syncthreads();

    // Layer-specialized wave shapes. Wave i -> SIMD i&3 (round-robin), so each
    // SIMD hosts one L0 wave (short MFMA burst) + one L1 wave (long burst):
    //   SIMD0: w0(16 MFMA)+w4(24)   SIMD1: w1(12)+w5(24)
    //   SIMD2: w2(12)+w6(24)        SIMD3: w3(12,+x)+w7(32)
    if (w == 0) {
        const int l0t[4] = {0, 1, 2, 3};
        run_loop<0, 4, false>(nullptr, l0t, b0, lane, quad, col, bP, h1f, x,
                              Wih0, Whh0, bih0, bhh0, Wih1, Whh1, bih1, bhh1);
    } else if (w == 1) {
        const int l0t[3] = {4, 5, 6};
        run_loop<0, 3, false>(nullptr, l0t, b0, lane, quad, col, bP, h1f, x,
                              Wih0, Whh0, bih0, bhh0, Wih1, Whh1, bih1, bhh1);
    } else if (w == 2) {
        const int l0t[3] = {7, 8, 9};
        run_loop<0, 3, false>(nullptr, l0t, b0, lane, quad, col, bP, h1f, x,
                              Wih0, Whh0, bih0, bhh0, Wih1, Whh1, bih1, bhh1);
    } else if (w == 3) {
        const int l0t[3] = {10, 11, 12};
        run_loop<0, 3, true>(nullptr, l0t, b0, lane, quad, col, bP, h1f, x,
                             Wih0, Whh0, bih0, bhh0, Wih1, Whh1, bih1, bhh1);
    } else if (w == 7) {
        const int l1t[4] = {9, 10, 11, 12};
        run_loop<4, 0, false>(l1t, nullptr, b0, lane, quad, col, bP, h1f, x,
                              Wih0, Whh0, bih0, bhh0, Wih1, Whh1, bih1, bhh1);
    } else {
        const int l1t[3] = {3 * (w - 4), 3 * (w - 4) + 1, 3 * (w - 4) + 2};
        run_loop<3, 0, false>(l1t, nullptr, b0, lane, quad, col, bP, h1f, x,
                              Wih0, Whh0, bih0, bhh0, Wih1, Whh1, bih1, bhh1);
    }
    __syncthreads();

    // ---- head: out[b] = h1_last . Wlin + blin (fp32 path) ----
    if (tid < BB) {
        float o = blin[0];
        #pragma unroll
        for (int k = 0; k < Hn; ++k) o += Wlin[k] * h1f[k * 8 + tid];
        out[b0 + tid] = o;
    }
}

extern "C" void kernel_launch(void* const* d_in, const int* in_sizes, int n_in,
                              void* d_out, int out_size, void* d_ws, size_t ws_size,
                              hipStream_t stream) {
    const float* x    = (const float*)d_in[0];
    const float* Wih0 = (const float*)d_in[1];
    const float* Whh0 = (const float*)d_in[2];
    const float* bih0 = (const float*)d_in[3];
    const float* bhh0 = (const float*)d_in[4];
    const float* Wih1 = (const float*)d_in[5];
    const float* Whh1 = (const float*)d_in[6];
    const float* bih1 = (const float*)d_in[7];
    const float* bhh1 = (const float*)d_in[8];
    const float* Wlin = (const float*)d_in[9];
    const float* blin = (const float*)d_in[10];
    float* out = (float*)d_out;

    lstm2_kernel<<<NBLK, 512, 0, stream>>>(x, Wih0, Whh0, bih0, bhh0,
                                           Wih1, Whh1, bih1, bhh1,
                                           Wlin, blin, out);
}

// Round 5
// 427.640 us; speedup vs baseline: 2.7289x; 1.1017x over previous
//
#include <hip/hip_runtime.h>
#include <math.h>

#define Hn 50
#define Dn 8
#define Tn 512
#define BB 8               // batches per block
#define NBLK 256           // 2048/8 -> 1 block/CU
#define KST 136            // bP row stride (shorts): 128 + 8 pad

typedef __attribute__((ext_vector_type(8))) short short8;   // 8 bf16 (4 VGPRs)
typedef __attribute__((ext_vector_type(4))) float f32x4;

__device__ __forceinline__ float fexp2_(float x) {
#if __has_builtin(__builtin_amdgcn_exp2f)
    return __builtin_amdgcn_exp2f(x);
#else
    return exp2f(x);
#endif
}
__device__ __forceinline__ float frcp_(float x) {
#if __has_builtin(__builtin_amdgcn_rcpf)
    return __builtin_amdgcn_rcpf(x);
#else
    return 1.0f / x;
#endif
}
__device__ __forceinline__ float sigmoidf_(float x) {
    return frcp_(1.0f + fexp2_(-1.44269504f * x));
}
__device__ __forceinline__ float tanhf_(float x) {
    return 2.0f * sigmoidf_(2.0f * x) - 1.0f;
}
__device__ __forceinline__ float bf2f(short s) {
    return __uint_as_float(((unsigned)(unsigned short)s) << 16);
}
// truncation split: v = hi + lo + O(2^-17 v)
__device__ __forceinline__ void split_bf(float v, short& hi, short& lo) {
    hi = (short)(__float_as_uint(v) >> 16);
    const float r = v - bf2f(hi);
    lo = (short)(__float_as_uint(r) >> 16);
}
// in-register LSTM cell: g4 = (i,f,g,o) pre-activation, c = cell state
__device__ __forceinline__ float lstm_cell4(const f32x4 g4, float& c) {
    c = sigmoidf_(g4.y) * c + sigmoidf_(g4.x) * tanhf_(g4.z);
    return sigmoidf_(g4.w) * tanhf_(c);
}
__device__ __forceinline__ float shflxor8(float v) {
    return __shfl_xor(v, 8, 64);
}

// ============================================================================
// r17: r15/r16 transposed design at 4 WAVES/SIMD (1024-thread block).
// r16 post-mortem: VALUBusy CONTAINS MfmaUtil on CDNA (MFMA issues on the
// VALU port): pure VALU ~19%, MFMA ~32%, so ~49% of each 2133-cy step was
// IDLE (ds_read latency, shfl latency, MFMA chains, barrier) with only 2
// waves/SIMD to hide it. Fix = TLP: 16 waves/block, 1 block/CU, shorter
// per-wave chains, 4-way interleave per SIMD.
// Slot map (26 tiles): w0-7 = (L1 tile w + L0 tile w); w8-12 = L1 tile w;
// w13 = L0 {8,9}; w14 = L0 {10,11}; w15 = L0 {12} + x staging.
// Per-SIMD MFMA: 40/40/40/36. Worst-wave regs ~105 < 128 -> no spill at
// 4 waves/SIMD (tripwire: WRITE_SIZE balloons if wrong).
// Also hoisted out of the t-loop: bias col<8 masking (biasv), read/write
// LDS offsets, buffer base selects (scalar by uniform t).
// Everything else identical to r15/r16 (layouts, lag-1 L1, 1 barrier/step).
// K layout: k 0..49 = h0 | 50..57 = x | 64..113 = h1.
// C/D: n=lane&15 (batch: cols 0..7 hi, 8..15 lo), m=(lane>>4)*4+reg = the
// (i,f,g,o) of cell 4T+quad -> act fully in-register.
// ============================================================================

template<int NL1, int NL0, bool XD>
__device__ __forceinline__ void run_loop(
    const int* l1T, const int* l0T,
    int b0, int lane, int quad, int col,
    short (*bP)[16][KST], float* h1f, const float* x,
    const float* Wih0, const float* Whh0, const float* bih0, const float* bhh0,
    const float* Wih1, const float* Whh1, const float* bih1, const float* bhh1)
{
    constexpr int NS = NL1 + NL0;
    constexpr int NPAIR = (NS + 1) / 2;
    constexpr int NBF = (NL1 > 0) ? 4 : 2;

    short8 W1[NL1 > 0 ? NL1 : 1][4][2];   // [slot][kstep][hi/lo]
    short8 W0[NL0 > 0 ? NL0 : 1][2][2];
    f32x4  biasv[NS];   // pre-masked: bias in col<8 lanes, 0 elsewhere
    int    kb[NS];      // k index base for h-write: layer*64 + 4*T
    int    cellb[NS];   // cell base: 4*T

    // ---- stationary A-side weights: lane holds W[m=col][k=32s+quad*8+j] ----
    #pragma unroll
    for (int i = 0; i < NL1; ++i) {
        const int T = l1T[i];
        const int ng = T * 16 + col, cl = ng >> 2, g = ng & 3;
        const bool on = (cl < Hn);
        const int grow = g * Hn + cl;
        #pragma unroll
        for (int s = 0; s < 4; ++s)
            #pragma unroll
            for (int j = 0; j < 8; ++j) {
                const int k = 32 * s + quad * 8 + j;
                float v = 0.f;
                if (on) {
                    if (k < Hn)                      v = Wih1[grow * Hn + k];
                    else if (k >= 64 && k < 64 + Hn) v = Whh1[grow * Hn + (k - 64)];
                }
                short hi, lo; split_bf(v, hi, lo);
                W1[i][s][0][j] = hi; W1[i][s][1][j] = lo;
            }
        const int myc = 4 * T + quad;
        #pragma unroll
        for (int r = 0; r < 4; ++r)
            biasv[i][r] = ((myc < Hn) && (col < 8))
                        ? (bih1[r * Hn + myc] + bhh1[r * Hn + myc]) : 0.f;
        kb[i] = 64 + 4 * T; cellb[i] = 4 * T;
    }
    #pragma unroll
    for (int i = 0; i < NL0; ++i) {
        const int T = l0T[i];
        const int ng = T * 16 + col, cl = ng >> 2, g = ng & 3;
        const bool on = (cl < Hn);
        const int grow = g * Hn + cl;
        #pragma unroll
        for (int s = 0; s < 2; ++s)
            #pragma unroll
            for (int j = 0; j < 8; ++j) {
                const int k = 32 * s + quad * 8 + j;
                float v = 0.f;
                if (on) {
                    if (k < Hn)           v = Whh0[grow * Hn + k];
                    else if (k < Hn + Dn) v = Wih0[grow * Dn + (k - Hn)];
                }
                short hi, lo; split_bf(v, hi, lo);
                W0[i][s][0][j] = hi; W0[i][s][1][j] = lo;
            }
        const int myc = 4 * T + quad;
        #pragma unroll
        for (int r = 0; r < 4; ++r)
            biasv[NL1 + i][r] = ((myc < Hn) && (col < 8))
                              ? (bih0[r * Hn + myc] + bhh0[r * Hn + myc]) : 0.f;
        kb[NL1 + i] = 4 * T; cellb[NL1 + i] = 4 * T;
    }

    // ---- hoisted loop invariants ----
    const short* base0 = &bP[0][0][0];
    const short* base1 = &bP[1][0][0];
    int rdo[NBF];
    #pragma unroll
    for (int s = 0; s < NBF; ++s) rdo[s] = col * KST + 32 * s + quad * 8;

    int  wofH[NPAIR], wofL[NPAIR], wofS[NPAIR];
    bool actOK[NPAIR], lagged[NPAIR];
    #pragma unroll
    for (int p = 0; p < NPAIR; ++p) {
        const int ia = 2 * p;
        const bool hasB = (ia + 1 < NS);
        const int slot = (hasB && col >= 8) ? ia + 1 : ia;
        const int cell = cellb[slot] + quad;
        const int kc   = kb[slot] + quad;
        lagged[p] = (slot < NL1);
        actOK[p]  = (cell < Hn);
        wofH[p] = (col & 7) * KST + kc;
        wofL[p] = wofH[p] + 8 * KST;
        wofS[p] = col * KST + kc;
    }

    float c[NPAIR];
    #pragma unroll
    for (int p = 0; p < NPAIR; ++p) c[p] = 0.f;

    const float* xp = XD ? (x + (size_t)(b0 + (lane >> 3)) * Tn * Dn + (lane & 7))
                         : (const float*)nullptr;

    // ================= main loop: one phase (one barrier) per timestep ======
    for (int t = 0; t < Tn; ++t) {
        float xv = 0.f;
        if (XD) { if (t + 1 < Tn) xv = xp[(size_t)(t + 1) * Dn]; }   // issue early

        const short* rb = (t & 1) ? base1 : base0;      // scalar selects (t uniform)
        short* wb = (short*)((t & 1) ? base0 : base1);

        // B-side fragments: lane reads h[k=32s+quad*8 .. +7] for its n=col
        short8 BF[NBF];
        #pragma unroll
        for (int s = 0; s < NBF; ++s)
            BF[s] = *(const short8*)&rb[rdo[s]];

        f32x4 acc[NS];
        #pragma unroll
        for (int i = 0; i < NS; ++i) acc[i] = biasv[i];
        #pragma unroll
        for (int i = 0; i < NL1; ++i)
            #pragma unroll
            for (int s = 0; s < 4; ++s) {
                acc[i] = __builtin_amdgcn_mfma_f32_16x16x32_bf16(W1[i][s][0], BF[s], acc[i], 0, 0, 0);
                acc[i] = __builtin_amdgcn_mfma_f32_16x16x32_bf16(W1[i][s][1], BF[s], acc[i], 0, 0, 0);
            }
        #pragma unroll
        for (int i = 0; i < NL0; ++i)
            #pragma unroll
            for (int s = 0; s < 2; ++s) {
                acc[NL1 + i] = __builtin_amdgcn_mfma_f32_16x16x32_bf16(W0[i][s][0], BF[s], acc[NL1 + i], 0, 0, 0);
                acc[NL1 + i] = __builtin_amdgcn_mfma_f32_16x16x32_bf16(W0[i][s][1], BF[s], acc[NL1 + i], 0, 0, 0);
            }

        // ---- in-register act: paired slots, u/v single-shfl merge ----
        #pragma unroll
        for (int p = 0; p < NPAIR; ++p) {
            const int ia = 2 * p;
            const bool hasB = (ia + 1 < NS);
            f32x4 g;
            #pragma unroll
            for (int r = 0; r < 4; ++r) {
                if (hasB) {
                    const float u = (col < 8) ? acc[ia][r]     : acc[ia + 1][r];
                    const float v = (col < 8) ? acc[ia + 1][r] : acc[ia][r];
                    g[r] = u + shflxor8(v);
                } else {
                    g[r] = acc[ia][r] + shflxor8(acc[ia][r]);
                }
            }
            const bool doAct = actOK[p] && ((t >= 1) || !lagged[p]);  // L1 lags 1
            if (doAct) {
                const float h = lstm_cell4(g, c[p]);
                short hi, lo; split_bf(h, hi, lo);
                if (hasB) { wb[wofH[p]] = hi; wb[wofL[p]] = lo; }
                else      { wb[wofS[p]] = (col < 8) ? hi : lo; }
            }
        }
        if (XD) {
            if (t + 1 < Tn) {
                short hi, lo; split_bf(xv, hi, lo);
                wb[(lane >> 3) * KST + Hn + (lane & 7)]       = hi;
                wb[((lane >> 3) + 8) * KST + Hn + (lane & 7)] = lo;
            }
        }
        __syncthreads();
    }

    // ======== epilogue phase: gates1(Tn-1) + act1 -> h1f (fp32) ========
    if constexpr (NL1 > 0) {
        const short* rb = base0;   // Tn even -> bP[0]
        short8 BF[4];
        #pragma unroll
        for (int s = 0; s < 4; ++s)
            BF[s] = *(const short8*)&rb[col * KST + 32 * s + quad * 8];
        f32x4 accE[NL1];
        #pragma unroll
        for (int i = 0; i < NL1; ++i) accE[i] = biasv[i];
        #pragma unroll
        for (int i = 0; i < NL1; ++i)
            #pragma unroll
            for (int s = 0; s < 4; ++s) {
                accE[i] = __builtin_amdgcn_mfma_f32_16x16x32_bf16(W1[i][s][0], BF[s], accE[i], 0, 0, 0);
                accE[i] = __builtin_amdgcn_mfma_f32_16x16x32_bf16(W1[i][s][1], BF[s], accE[i], 0, 0, 0);
            }
        #pragma unroll
        for (int p = 0; p < NPAIR; ++p) {
            const int ia = 2 * p;
            if (ia < NL1) {
                const bool bL1 = (ia + 1 < NL1);
                f32x4 g;
                #pragma unroll
                for (int r = 0; r < 4; ++r) {
                    if (bL1) {
                        const float u = (col < 8) ? accE[ia][r]     : accE[ia + 1][r];
                        const float v = (col < 8) ? accE[ia + 1][r] : accE[ia][r];
                        g[r] = u + shflxor8(v);
                    } else {
                        g[r] = accE[ia][r] + shflxor8(accE[ia][r]);
                    }
                }
                int cell; bool mine;
                if (bL1) { cell = ((col < 8) ? cellb[ia] : cellb[ia + 1]) + quad; mine = true; }
                else     { cell = cellb[ia] + quad;                               mine = (col < 8); }
                if (mine && cell < Hn) {
                    const float h = lstm_cell4(g, c[p]);
                    h1f[cell * 8 + (col & 7)] = h;
                }
            }
        }
    }
}

__global__ __launch_bounds__(1024) void lstm2_kernel(
    const float* __restrict__ x,
    const float* __restrict__ Wih0, const float* __restrict__ Whh0,
    const float* __restrict__ bih0, const float* __restrict__ bhh0,
    const float* __restrict__ Wih1, const float* __restrict__ Whh1,
    const float* __restrict__ bih1, const float* __restrict__ bhh1,
    const float* __restrict__ Wlin, const float* __restrict__ blin,
    float* __restrict__ out)
{
    const int tid  = threadIdx.x;     // 0..1023
    const int b0   = blockIdx.x * BB;
    // readfirstlane: wave index SGPR-uniform so shape dispatch is scalar —
    // __syncthreads lives inside the branches (equal counts in all arms).
    const int w    = __builtin_amdgcn_readfirstlane(tid >> 6);   // 0..15
    const int lane = tid & 63;
    const int quad = lane >> 4;
    const int col  = lane & 15;

    __shared__ __align__(16) short bP[2][16][KST];   // double-buffered h/x pack
    __shared__ float h1f[Hn * 8];                    // fp32 h1 at t=Tn-1

    // ---- init: zero both buffers (initial h0/h1 = 0); stage x(0) ----
    for (int i = tid; i < 2 * 16 * KST; i += 1024) (&bP[0][0][0])[i] = 0;
    __syncthreads();
    if (tid < 64) {
        const int xb = tid >> 3, xd = tid & 7;
        const float f = x[((size_t)(b0 + xb) * Tn + 0) * Dn + xd];
        short hi, lo; split_bf(f, hi, lo);
        bP[0][xb][Hn + xd]     = hi;
        bP[0][xb + 8][Hn + xd] = lo;
    }
    __syncthreads();

    // 16 waves, wave i -> SIMD i&3: each SIMD hosts 4 waves with mixed
    // short/long MFMA bursts. Per-SIMD MFMA totals: 40/40/40/36.
    if (w < 8) {
        const int l1t[1] = {w};
        const int l0t[1] = {w};
        run_loop<1, 1, false>(l1t, l0t, b0, lane, quad, col, bP, h1f, x,
                              Wih0, Whh0, bih0, bhh0, Wih1, Whh1, bih1, bhh1);
    } else if (w < 13) {
        const int l1t[1] = {w};      // L1 tiles 8..12
        run_loop<1, 0, false>(l1t, nullptr, b0, lane, quad, col, bP, h1f, x,
                              Wih0, Whh0, bih0, bhh0, Wih1, Whh1, bih1, bhh1);
    } else if (w == 13) {
        const int l0t[2] = {8, 9};
        run_loop<0, 2, false>(nullptr, l0t, b0, lane, quad, col, bP, h1f, x,
                              Wih0, Whh0, bih0, bhh0, Wih1, Whh1, bih1, bhh1);
    } else if (w == 14) {
        const int l0t[2] = {10, 11};
        run_loop<0, 2, false>(nullptr, l0t, b0, lane, quad, col, bP, h1f, x,
                              Wih0, Whh0, bih0, bhh0, Wih1, Whh1, bih1, bhh1);
    } else {
        const int l0t[1] = {12};
        run_loop<0, 1, true>(nullptr, l0t, b0, lane, quad, col, bP, h1f, x,
                             Wih0, Whh0, bih0, bhh0, Wih1, Whh1, bih1, bhh1);
    }
    __syncthreads();

    // ---- head: out[b] = h1_last . Wlin + blin (fp32 path) ----
    if (tid < BB) {
        float o = blin[0];
        #pragma unroll
        for (int k = 0; k < Hn; ++k) o += Wlin[k] * h1f[k * 8 + tid];
        out[b0 + tid] = o;
    }
}

extern "C" void kernel_launch(void* const* d_in, const int* in_sizes, int n_in,
                              void* d_out, int out_size, void* d_ws, size_t ws_size,
                              hipStream_t stream) {
    const float* x    = (const float*)d_in[0];
    const float* Wih0 = (const float*)d_in[1];
    const float* Whh0 = (const float*)d_in[2];
    const float* bih0 = (const float*)d_in[3];
    const float* bhh0 = (const float*)d_in[4];
    const float* Wih1 = (const float*)d_in[5];
    const float* Whh1 = (const float*)d_in[6];
    const float* bih1 = (const float*)d_in[7];
    const float* bhh1 = (const float*)d_in[8];
    const float* Wlin = (const float*)d_in[9];
    const float* blin = (const float*)d_in[10];
    float* out = (float*)d_out;

    lstm2_kernel<<<NBLK, 1024, 0, stream>>>(x, Wih0, Whh0, bih0, bhh0,
                                            Wih1, Whh1, bih1, bhh1,
                                            Wlin, blin, out);
}